// Round 3
// baseline (1051.454 us; speedup 1.0000x reference)
//
#include <hip/hip_runtime.h>
#include <hip/hip_bf16.h>

// DFFN fused implementation. R3: proj_in GEMM moved to bf16 MFMA with
// hi/lo-split operands (fp32-accurate: x_hi*w_hi + x_lo*w_hi + x_hi*w_lo);
// circular conv stays on VALU; ysT LDS now bf16 (50.3 KB total -> 3 blocks/CU).
// Pipeline: proj_in(1x1) -> per-channel 8x8 circular conv (== rfft2*filter*
// irfft2 on the flat-reshaped "patches" = 1x64 column runs) -> dw3x3 -> GELU
// gate -> proj_out(1x1).  Intermediate s: channels-last bf16 [b][h][w][c2].

#define BATCH 4
#define CIN   64
#define C2    256
#define HH    256
#define WW    256
#define HW    (HH*WW)

using bf16 = __hip_bfloat16;
typedef short bf16x8 __attribute__((ext_vector_type(8)));
typedef float f32x4  __attribute__((ext_vector_type(4)));

__device__ __forceinline__ float bf2f(bf16 v){ return __bfloat162float(v); }
__device__ __forceinline__ unsigned f2bf_bits(float v){
    unsigned u = __float_as_uint(v);
    return (u + 0x7fffu + ((u >> 16) & 1u)) >> 16;          // RNE
}
__device__ __forceinline__ float bfbits2f(unsigned hu){ return __uint_as_float(hu << 16); }

__device__ __forceinline__ void unpack8(uint4 v, float* f) {
    unsigned a0 = v.x, a1 = v.y, a2 = v.z, a3 = v.w;
    f[0] = __uint_as_float(a0 << 16); f[1] = __uint_as_float(a0 & 0xffff0000u);
    f[2] = __uint_as_float(a1 << 16); f[3] = __uint_as_float(a1 & 0xffff0000u);
    f[4] = __uint_as_float(a2 << 16); f[5] = __uint_as_float(a2 & 0xffff0000u);
    f[6] = __uint_as_float(a3 << 16); f[7] = __uint_as_float(a3 & 0xffff0000u);
}

// ---------------------------------------------------------------------------
// K0: per-channel 8x8 circular-conv kernel from the rfft2 half-spectrum filter.
// K[m,n] = sum_v w_v * (ReG_v[m]*cos(v*n*pi/4) - ImG_v[m]*sin(v*n*pi/4))
// G_v[m] = (1/8) sum_u F[u,v] * e^{i*u*m*pi/4};  w_0=w_4=1/8, w_1..3=1/4.
// ---------------------------------------------------------------------------
__global__ void k_precompute(const float* __restrict__ F, float* __restrict__ Kc)
{
    const int c = threadIdx.x;                   // 256 threads = 256 channels
    const float R = 0.7071067811865476f;
    const float C8[8] = {1.f, R, 0.f, -R, -1.f, -R, 0.f, R};
    const float S8[8] = {0.f, R, 1.f, R, 0.f, -R, -1.f, -R};

    float Fv[8][5];
    for (int u = 0; u < 8; ++u)
        for (int v = 0; v < 5; ++v)
            Fv[u][v] = F[c*40 + u*5 + v];

    float ReG[5][8], ImG[5][8];
    for (int v = 0; v < 5; ++v)
        for (int m = 0; m < 8; ++m) {
            float re = 0.f, im = 0.f;
            for (int u = 0; u < 8; ++u) {
                int idx = (u*m) & 7;
                re += Fv[u][v] * C8[idx];
                im += Fv[u][v] * S8[idx];
            }
            ReG[v][m] = re * 0.125f;
            ImG[v][m] = im * 0.125f;
        }

    for (int m = 0; m < 8; ++m)
        for (int n = 0; n < 8; ++n) {
            float acc = 0.f;
            for (int v = 0; v < 5; ++v) {
                float wv = (v == 0 || v == 4) ? 0.125f : 0.25f;
                int idx = (v*n) & 7;
                acc += wv * (ReG[v][m]*C8[idx] - ImG[v][m]*S8[idx]);
            }
            Kc[c*64 + m*8 + n] = acc;
        }
}

// ---------------------------------------------------------------------------
// K1: per (b, h, 64-col run): proj_in via MFMA (m=px16, n=c2, k=cin) with
// hi/lo bf16 split, then VALU circular conv, bf16 channels-last store.
// LDS: xs_hi/xs_lo [px][cin] stride 72 (b128 frag loads, conflict-free),
//      ysT bf16 [px=64][c2] stride 258.
// ---------------------------------------------------------------------------
__global__ __launch_bounds__(256, 3) void k1_proj_circ(
    const float* __restrict__ x, const float* __restrict__ w_in,
    const float* __restrict__ b_in, const float* __restrict__ Kc,
    bf16* __restrict__ s)
{
    __shared__ __align__(16) unsigned short xs_hi[64*72];   // 9 KB
    __shared__ __align__(16) unsigned short xs_lo[64*72];   // 9 KB
    __shared__ __align__(16) unsigned short ysT[64*258];    // 32.25 KB

    const int tid = threadIdx.x;
    const int bid = blockIdx.x;
    const int run = bid & 3;
    const int h   = (bid >> 2) & 255;
    const int b   = bid >> 10;

    const float* xb = x + (long)b * CIN * HW + h * WW + run * 64;

    // stage x tile (64 cin x 64 px), hi/lo bf16 split, transposed [px][cin]
#pragma unroll
    for (int i = 0; i < 16; ++i) {
        int e = i*256 + tid;
        int c = e >> 6, col = e & 63;
        float v = xb[(long)c * HW + col];
        unsigned hu = f2bf_bits(v);
        float hf = bfbits2f(hu);
        unsigned lu = f2bf_bits(v - hf);
        xs_hi[col*72 + c] = (unsigned short)hu;
        xs_lo[col*72 + c] = (unsigned short)lu;
    }
    __syncthreads();

    const int wv = tid >> 6, lane = tid & 63;
    const int quad = lane >> 4, n16 = lane & 15;

    // A fragments: A[m=px][k=cin], lane m = n16, elems k = quad*8+j
    bf16x8 ah[4][2], al[4][2];
#pragma unroll
    for (int mt = 0; mt < 4; ++mt)
#pragma unroll
        for (int k = 0; k < 2; ++k) {
            int o = (mt*16 + n16)*72 + k*32 + quad*8;
            ah[mt][k] = *(const bf16x8*)&xs_hi[o];
            al[mt][k] = *(const bf16x8*)&xs_lo[o];
        }

    // wave wv handles c2 in [wv*64, wv*64+64)
#pragma unroll
    for (int nt = 0; nt < 4; ++nt) {
        const int c2 = wv*64 + nt*16 + n16;
        f32x4 acc[4];
#pragma unroll
        for (int mt = 0; mt < 4; ++mt) acc[mt] = (f32x4){0.f,0.f,0.f,0.f};

#pragma unroll
        for (int k = 0; k < 2; ++k) {
            // B[k=cin][n=c2] = w_in[c2][cin]; lane n = n16, elems k = quad*8+j
            const float* wp = w_in + c2*64 + k*32 + quad*8;
            float wf[8];
            *(float4*)&wf[0] = *(const float4*)wp;
            *(float4*)&wf[4] = *(const float4*)(wp + 4);
            bf16x8 bh, bl;
#pragma unroll
            for (int j = 0; j < 8; ++j) {
                unsigned hu = f2bf_bits(wf[j]);
                bh[j] = (short)hu;
                bl[j] = (short)f2bf_bits(wf[j] - bfbits2f(hu));
            }
#pragma unroll
            for (int mt = 0; mt < 4; ++mt) {
                acc[mt] = __builtin_amdgcn_mfma_f32_16x16x32_bf16(ah[mt][k], bh, acc[mt], 0, 0, 0);
                acc[mt] = __builtin_amdgcn_mfma_f32_16x16x32_bf16(al[mt][k], bh, acc[mt], 0, 0, 0);
                acc[mt] = __builtin_amdgcn_mfma_f32_16x16x32_bf16(ah[mt][k], bl, acc[mt], 0, 0, 0);
            }
        }
        // epilogue: + bias, bf16, into ysT[px][c2]
        float bv = b_in[c2];
#pragma unroll
        for (int mt = 0; mt < 4; ++mt)
#pragma unroll
            for (int r = 0; r < 4; ++r) {
                int u = mt*16 + quad*4 + r;       // D row = quad*4 + reg
                ysT[u*258 + c2] = (unsigned short)f2bf_bits(acc[mt][r] + bv);
            }
    }
    __syncthreads();

    // circular conv: thread = channel tid
    const float* Kp = Kc + tid*64;
    float o[64];
#pragma unroll
    for (int i = 0; i < 64; ++i) o[i] = 0.f;

#pragma unroll
    for (int a = 0; a < 8; ++a) {
        for (int m = 0; m < 8; ++m) {
            int r = (a - m) & 7;
            float yy[8];
#pragma unroll
            for (int q = 0; q < 8; ++q)
                yy[q] = bfbits2f((unsigned)ysT[(r*8 + q)*258 + tid]);
#pragma unroll
            for (int n = 0; n < 8; ++n) {
                float kk = Kp[m*8 + n];
#pragma unroll
                for (int bb = 0; bb < 8; ++bb)
                    o[a*8 + bb] += kk * yy[(bb - n) & 7];
            }
        }
    }

    // write back into own column (only this thread touches column tid)
#pragma unroll
    for (int u = 0; u < 64; ++u)
        ysT[u*258 + tid] = (unsigned short)f2bf_bits(o[u]);
    __syncthreads();

    // channels-last coalesced store: s[((b*HH+h)*WW + run*64+u)*C2 + c]
    bf16* sp = s + (((long)(b * HH + h) * WW) + run * 64) * C2;
    const int uo = tid >> 5;          // 0..7
    const int c0 = (tid & 31) * 8;    // 0..248
#pragma unroll
    for (int pass = 0; pass < 8; ++pass) {
        int u = pass * 8 + uo;
        const unsigned* yp = (const unsigned*)&ysT[u*258 + c0];
        uint4 val = make_uint4(yp[0], yp[1], yp[2], yp[3]);
        *(uint4*)(sp + (long)u * C2 + c0) = val;
    }
}

// ---------------------------------------------------------------------------
// K2: per (b, h, run of 64 px): dw3x3 + bias -> GELU gate -> proj_out (128->64).
// s is channels-last. Phase 1: thread = (px=lane, chunk-pair of 8 ch), 4 tasks;
// 18 x 16B global loads per task. g stored transposed in LDS [c][px] stride 65.
// Phase 2: wave rg -> out channels rg*16..+15, lane = px.
// ---------------------------------------------------------------------------
__global__ __launch_bounds__(256, 4) void k2_dw_gelu_out(
    const bf16* __restrict__ s, const float* __restrict__ w_dw,
    const float* __restrict__ b_dw, const float* __restrict__ w_out,
    const float* __restrict__ b_out, float* __restrict__ out)
{
    __shared__ float tb[128*65];   // 33.3 KB: g[c][px], stride 65

    const int tid = threadIdx.x;
    const int l   = ((blockIdx.x & 7) << 9) | (blockIdx.x >> 3);  // XCD swizzle
    const int run = l & 3;
    const int h   = (l >> 2) & 255;
    const int b   = l >> 10;
    const int wl  = tid & 63, rg = tid >> 6;
    const int w   = run*64 + wl;

#pragma unroll
    for (int i = 0; i < 4; ++i) {
        const int c0 = __builtin_amdgcn_readfirstlane((rg + 4*i) * 8); // 0..120, uniform
        float t1[8], t2[8];
#pragma unroll
        for (int j = 0; j < 8; ++j) { t1[j] = b_dw[c0+j]; t2[j] = b_dw[c0+128+j]; }

#pragma unroll
        for (int dy = 0; dy < 3; ++dy) {
            const int hy = h + dy - 1;
            if ((unsigned)hy >= HH) continue;          // wave-uniform
#pragma unroll
            for (int dx = 0; dx < 3; ++dx) {
                const int wx = w + dx - 1;
                if ((unsigned)wx < WW) {               // diverges only at image edge
                    const bf16* p = s + (((long)(b*HH + hy)*WW + wx) * C2 + c0);
                    uint4 v1 = *(const uint4*)p;
                    uint4 v2 = *(const uint4*)(p + 128);
                    float f1[8], f2[8];
                    unpack8(v1, f1); unpack8(v2, f2);
#pragma unroll
                    for (int j = 0; j < 8; ++j) {
                        t1[j] += f1[j] * w_dw[(c0+j)*9       + dy*3 + dx];
                        t2[j] += f2[j] * w_dw[(c0+128+j)*9   + dy*3 + dx];
                    }
                }
            }
        }
        // GELU(t1)*t2, exact erf; store transposed
#pragma unroll
        for (int j = 0; j < 8; ++j) {
            float g = t1[j] * 0.5f * (1.0f + erff(t1[j] * 0.7071067811865476f)) * t2[j];
            tb[(c0 + j)*65 + wl] = g;
        }
    }
    __syncthreads();

    // proj_out: wave rg handles out channels rg*16 .. rg*16+15, lane = px
    const int og = __builtin_amdgcn_readfirstlane(rg);
    float acc[16];
#pragma unroll
    for (int i = 0; i < 16; ++i) acc[i] = b_out[og*16 + i];
    for (int c = 0; c < 128; c += 4) {
        float g0 = tb[(c+0)*65 + wl];
        float g1 = tb[(c+1)*65 + wl];
        float g2 = tb[(c+2)*65 + wl];
        float g3 = tb[(c+3)*65 + wl];
#pragma unroll
        for (int i = 0; i < 16; ++i) {
            const float4 wv = *(const float4*)&w_out[(og*16 + i)*128 + c];
            acc[i] += g0*wv.x + g1*wv.y + g2*wv.z + g3*wv.w;
        }
    }
    float* op = out + (long)b * CIN * HW + h * WW + w;
#pragma unroll
    for (int i = 0; i < 16; ++i)
        op[(long)(og*16 + i) * HW] = acc[i];
}

// ---------------------------------------------------------------------------
extern "C" void kernel_launch(void* const* d_in, const int* in_sizes, int n_in,
                              void* d_out, int out_size, void* d_ws, size_t ws_size,
                              hipStream_t stream) {
    const float* x     = (const float*)d_in[0];
    const float* w_in  = (const float*)d_in[1];
    const float* b_in  = (const float*)d_in[2];
    const float* ff    = (const float*)d_in[3];
    const float* w_dw  = (const float*)d_in[4];
    const float* b_dw  = (const float*)d_in[5];
    const float* w_out = (const float*)d_in[6];
    const float* b_out = (const float*)d_in[7];
    float* out = (float*)d_out;

    float* Kc = (float*)d_ws;                           // 64 KB
    bf16*  s  = (bf16*)((char*)d_ws + 65536);           // 128 MB intermediate

    hipLaunchKernelGGL(k_precompute,   dim3(1),    dim3(256), 0, stream, ff, Kc);
    hipLaunchKernelGGL(k1_proj_circ,   dim3(4096), dim3(256), 0, stream,
                       x, w_in, b_in, Kc, s);
    hipLaunchKernelGGL(k2_dw_gelu_out, dim3(4096), dim3(256), 0, stream,
                       s, w_dw, b_dw, w_out, b_out, out);
}

// Round 4
// 554.658 us; speedup vs baseline: 1.8957x; 1.8957x over previous
//
#include <hip/hip_runtime.h>
#include <hip/hip_bf16.h>

// DFFN fused implementation. R4: fix R3's register-spill catastrophe (2.84 GB
// scratch traffic) while keeping the MFMA proj_in:
//  - nt loop rolled, A-frags re-read from LDS per (nt,k), only acc[] lives.
//  - hi/lo bf16 split of w_in precomputed by k0 into scratch carved from d_out
//    (k2 fully overwrites d_out afterwards), so k1 has zero B-build VALU.
// Pipeline: proj_in(1x1, MFMA hi/lo bf16 = fp32-accurate) -> per-channel 8x8
// circular conv (== rfft2*filter*irfft2 on the flat-reshaped "patches" = 1x64
// column runs) -> dw3x3 -> GELU gate -> proj_out(1x1).
// Intermediate s: channels-last bf16 [b][h][w][c2].

#define BATCH 4
#define CIN   64
#define C2    256
#define HH    256
#define WW    256
#define HW    (HH*WW)

using bf16 = __hip_bfloat16;
typedef short bf16x8 __attribute__((ext_vector_type(8)));
typedef float f32x4  __attribute__((ext_vector_type(4)));

__device__ __forceinline__ unsigned f2bf_bits(float v){
    unsigned u = __float_as_uint(v);
    return (u + 0x7fffu + ((u >> 16) & 1u)) >> 16;          // RNE
}
__device__ __forceinline__ float bfbits2f(unsigned hu){ return __uint_as_float(hu << 16); }

__device__ __forceinline__ void unpack8(uint4 v, float* f) {
    unsigned a0 = v.x, a1 = v.y, a2 = v.z, a3 = v.w;
    f[0] = __uint_as_float(a0 << 16); f[1] = __uint_as_float(a0 & 0xffff0000u);
    f[2] = __uint_as_float(a1 << 16); f[3] = __uint_as_float(a1 & 0xffff0000u);
    f[4] = __uint_as_float(a2 << 16); f[5] = __uint_as_float(a2 & 0xffff0000u);
    f[6] = __uint_as_float(a3 << 16); f[7] = __uint_as_float(a3 & 0xffff0000u);
}

// ---------------------------------------------------------------------------
// K0: (a) per-channel 8x8 circular-conv kernel from the rfft2 filter;
//     (b) hi/lo bf16 split of w_in into B-operand tables whi/wlo [c2][cin].
// ---------------------------------------------------------------------------
__global__ void k_precompute(const float* __restrict__ F,
                             const float* __restrict__ w_in,
                             float* __restrict__ Kc,
                             unsigned short* __restrict__ whi,
                             unsigned short* __restrict__ wlo)
{
    const int c = threadIdx.x;                   // 256 threads = 256 channels
    const float R = 0.7071067811865476f;
    const float C8[8] = {1.f, R, 0.f, -R, -1.f, -R, 0.f, R};
    const float S8[8] = {0.f, R, 1.f, R, 0.f, -R, -1.f, -R};

    // (b) w_in split
    for (int k = 0; k < 64; ++k) {
        float v = w_in[c*64 + k];
        unsigned hu = f2bf_bits(v);
        whi[c*64 + k] = (unsigned short)hu;
        wlo[c*64 + k] = (unsigned short)f2bf_bits(v - bfbits2f(hu));
    }

    // (a) conv kernel
    float Fv[8][5];
    for (int u = 0; u < 8; ++u)
        for (int v = 0; v < 5; ++v)
            Fv[u][v] = F[c*40 + u*5 + v];

    float ReG[5][8], ImG[5][8];
    for (int v = 0; v < 5; ++v)
        for (int m = 0; m < 8; ++m) {
            float re = 0.f, im = 0.f;
            for (int u = 0; u < 8; ++u) {
                int idx = (u*m) & 7;
                re += Fv[u][v] * C8[idx];
                im += Fv[u][v] * S8[idx];
            }
            ReG[v][m] = re * 0.125f;
            ImG[v][m] = im * 0.125f;
        }

    for (int m = 0; m < 8; ++m)
        for (int n = 0; n < 8; ++n) {
            float acc = 0.f;
            for (int v = 0; v < 5; ++v) {
                float wv = (v == 0 || v == 4) ? 0.125f : 0.25f;
                int idx = (v*n) & 7;
                acc += wv * (ReG[v][m]*C8[idx] - ImG[v][m]*S8[idx]);
            }
            Kc[c*64 + m*8 + n] = acc;
        }
}

// ---------------------------------------------------------------------------
// K1: per (b, h, 64-col run): proj_in via MFMA (m=px16, n=c2, k=cin) with
// hi/lo bf16 split (x_hi*w_hi + x_lo*w_hi + x_hi*w_lo), then VALU circular
// conv, bf16 channels-last store.
// Register hygiene: nt loop rolled, A-frags re-read from LDS each (nt,k),
// B-frags are direct 16B loads of precomputed whi/wlo. Only acc[4] persists.
// LDS: xs_hi/xs_lo [px][cin] stride 72, ysT bf16 [px][c2] stride 258. 50.25 KB.
// ---------------------------------------------------------------------------
__global__ __launch_bounds__(256) void k1_proj_circ(
    const float* __restrict__ x,
    const unsigned short* __restrict__ whi,
    const unsigned short* __restrict__ wlo,
    const float* __restrict__ b_in, const float* __restrict__ Kc,
    bf16* __restrict__ s)
{
    __shared__ __align__(16) unsigned short xs_hi[64*72];   // 9 KB
    __shared__ __align__(16) unsigned short xs_lo[64*72];   // 9 KB
    __shared__ __align__(16) unsigned short ysT[64*258];    // 32.25 KB

    const int tid = threadIdx.x;
    const int bid = blockIdx.x;
    const int run = bid & 3;
    const int h   = (bid >> 2) & 255;
    const int b   = bid >> 10;

    const float* xb = x + (long)b * CIN * HW + h * WW + run * 64;

    // stage x tile (64 cin x 64 px), hi/lo bf16 split, transposed [px][cin]
#pragma unroll
    for (int i = 0; i < 16; ++i) {
        int e = i*256 + tid;
        int c = e >> 6, col = e & 63;
        float v = xb[(long)c * HW + col];
        unsigned hu = f2bf_bits(v);
        unsigned lu = f2bf_bits(v - bfbits2f(hu));
        xs_hi[col*72 + c] = (unsigned short)hu;
        xs_lo[col*72 + c] = (unsigned short)lu;
    }
    __syncthreads();

    const int wv = tid >> 6, lane = tid & 63;
    const int quad = lane >> 4, n16 = lane & 15;

    // wave wv handles c2 in [wv*64, wv*64+64)
    for (int nt = 0; nt < 4; ++nt) {                 // rolled: low pressure
        const int c2 = wv*64 + nt*16 + n16;
        f32x4 acc[4];
#pragma unroll
        for (int mt = 0; mt < 4; ++mt) acc[mt] = (f32x4){0.f,0.f,0.f,0.f};

#pragma unroll
        for (int k = 0; k < 2; ++k) {
            // B[k=cin][n=c2] frag: precomputed, elems k = k*32+quad*8+j
            const bf16x8 bh = *(const bf16x8*)&whi[c2*64 + k*32 + quad*8];
            const bf16x8 bl = *(const bf16x8*)&wlo[c2*64 + k*32 + quad*8];
#pragma unroll
            for (int mt = 0; mt < 4; ++mt) {
                const int o = (mt*16 + n16)*72 + k*32 + quad*8;
                const bf16x8 a_h = *(const bf16x8*)&xs_hi[o];
                const bf16x8 a_l = *(const bf16x8*)&xs_lo[o];
                acc[mt] = __builtin_amdgcn_mfma_f32_16x16x32_bf16(a_h, bh, acc[mt], 0, 0, 0);
                acc[mt] = __builtin_amdgcn_mfma_f32_16x16x32_bf16(a_l, bh, acc[mt], 0, 0, 0);
                acc[mt] = __builtin_amdgcn_mfma_f32_16x16x32_bf16(a_h, bl, acc[mt], 0, 0, 0);
            }
        }
        // epilogue: + bias, bf16, into ysT[px][c2]
        const float bv = b_in[c2];
#pragma unroll
        for (int mt = 0; mt < 4; ++mt)
#pragma unroll
            for (int r = 0; r < 4; ++r) {
                int u = mt*16 + quad*4 + r;          // D row = quad*4 + reg
                ysT[u*258 + c2] = (unsigned short)f2bf_bits(acc[mt][r] + bv);
            }
    }
    __syncthreads();

    // circular conv: thread = channel tid
    const float* Kp = Kc + tid*64;
    float o[64];
#pragma unroll
    for (int i = 0; i < 64; ++i) o[i] = 0.f;

#pragma unroll
    for (int a = 0; a < 8; ++a) {
        for (int m = 0; m < 8; ++m) {
            int r = (a - m) & 7;
            float yy[8];
#pragma unroll
            for (int q = 0; q < 8; ++q)
                yy[q] = bfbits2f((unsigned)ysT[(r*8 + q)*258 + tid]);
#pragma unroll
            for (int n = 0; n < 8; ++n) {
                float kk = Kp[m*8 + n];
#pragma unroll
                for (int bb = 0; bb < 8; ++bb)
                    o[a*8 + bb] += kk * yy[(bb - n) & 7];
            }
        }
    }

    // write back into own column (only this thread touches column tid)
#pragma unroll
    for (int u = 0; u < 64; ++u)
        ysT[u*258 + tid] = (unsigned short)f2bf_bits(o[u]);
    __syncthreads();

    // channels-last coalesced store: s[((b*HH+h)*WW + run*64+u)*C2 + c]
    bf16* sp = s + (((long)(b * HH + h) * WW) + run * 64) * C2;
    const int uo = tid >> 5;          // 0..7
    const int c0 = (tid & 31) * 8;    // 0..248
#pragma unroll
    for (int pass = 0; pass < 8; ++pass) {
        int u = pass * 8 + uo;
        const unsigned* yp = (const unsigned*)&ysT[u*258 + c0];
        uint4 val = make_uint4(yp[0], yp[1], yp[2], yp[3]);
        *(uint4*)(sp + (long)u * C2 + c0) = val;
    }
}

// ---------------------------------------------------------------------------
// K2: per (b, h, run of 64 px): dw3x3 + bias -> GELU gate -> proj_out (128->64).
// s is channels-last. Phase 1: thread = (px=lane, chunk-pair of 8 ch), 4 tasks;
// 18 x 16B global loads per task. g stored transposed in LDS [c][px] stride 65.
// Phase 2: wave rg -> out channels rg*16..+15, lane = px.
// ---------------------------------------------------------------------------
__global__ __launch_bounds__(256, 4) void k2_dw_gelu_out(
    const bf16* __restrict__ s, const float* __restrict__ w_dw,
    const float* __restrict__ b_dw, const float* __restrict__ w_out,
    const float* __restrict__ b_out, float* __restrict__ out)
{
    __shared__ float tb[128*65];   // 33.3 KB: g[c][px], stride 65

    const int tid = threadIdx.x;
    const int l   = ((blockIdx.x & 7) << 9) | (blockIdx.x >> 3);  // XCD swizzle
    const int run = l & 3;
    const int h   = (l >> 2) & 255;
    const int b   = l >> 10;
    const int wl  = tid & 63, rg = tid >> 6;
    const int w   = run*64 + wl;

#pragma unroll
    for (int i = 0; i < 4; ++i) {
        const int c0 = __builtin_amdgcn_readfirstlane((rg + 4*i) * 8); // 0..120, uniform
        float t1[8], t2[8];
#pragma unroll
        for (int j = 0; j < 8; ++j) { t1[j] = b_dw[c0+j]; t2[j] = b_dw[c0+128+j]; }

#pragma unroll
        for (int dy = 0; dy < 3; ++dy) {
            const int hy = h + dy - 1;
            if ((unsigned)hy >= HH) continue;          // wave-uniform
#pragma unroll
            for (int dx = 0; dx < 3; ++dx) {
                const int wx = w + dx - 1;
                if ((unsigned)wx < WW) {               // diverges only at image edge
                    const bf16* p = s + (((long)(b*HH + hy)*WW + wx) * C2 + c0);
                    uint4 v1 = *(const uint4*)p;
                    uint4 v2 = *(const uint4*)(p + 128);
                    float f1[8], f2[8];
                    unpack8(v1, f1); unpack8(v2, f2);
#pragma unroll
                    for (int j = 0; j < 8; ++j) {
                        t1[j] += f1[j] * w_dw[(c0+j)*9       + dy*3 + dx];
                        t2[j] += f2[j] * w_dw[(c0+128+j)*9   + dy*3 + dx];
                    }
                }
            }
        }
        // GELU(t1)*t2, exact erf; store transposed
#pragma unroll
        for (int j = 0; j < 8; ++j) {
            float g = t1[j] * 0.5f * (1.0f + erff(t1[j] * 0.7071067811865476f)) * t2[j];
            tb[(c0 + j)*65 + wl] = g;
        }
    }
    __syncthreads();

    // proj_out: wave rg handles out channels rg*16 .. rg*16+15, lane = px
    const int og = __builtin_amdgcn_readfirstlane(rg);
    float acc[16];
#pragma unroll
    for (int i = 0; i < 16; ++i) acc[i] = b_out[og*16 + i];
    for (int c = 0; c < 128; c += 4) {
        float g0 = tb[(c+0)*65 + wl];
        float g1 = tb[(c+1)*65 + wl];
        float g2 = tb[(c+2)*65 + wl];
        float g3 = tb[(c+3)*65 + wl];
#pragma unroll
        for (int i = 0; i < 16; ++i) {
            const float4 wv = *(const float4*)&w_out[(og*16 + i)*128 + c];
            acc[i] += g0*wv.x + g1*wv.y + g2*wv.z + g3*wv.w;
        }
    }
    float* op = out + (long)b * CIN * HW + h * WW + w;
#pragma unroll
    for (int i = 0; i < 16; ++i)
        op[(long)(og*16 + i) * HW] = acc[i];
}

// ---------------------------------------------------------------------------
extern "C" void kernel_launch(void* const* d_in, const int* in_sizes, int n_in,
                              void* d_out, int out_size, void* d_ws, size_t ws_size,
                              hipStream_t stream) {
    const float* x     = (const float*)d_in[0];
    const float* w_in  = (const float*)d_in[1];
    const float* b_in  = (const float*)d_in[2];
    const float* ff    = (const float*)d_in[3];
    const float* w_dw  = (const float*)d_in[4];
    const float* b_dw  = (const float*)d_in[5];
    const float* w_out = (const float*)d_in[6];
    const float* b_out = (const float*)d_in[7];
    float* out = (float*)d_out;

    float* Kc = (float*)d_ws;                           // 64 KB
    bf16*  s  = (bf16*)((char*)d_ws + 65536);           // 128 MB intermediate

    // 64 KB of B-operand tables carved from d_out (64 MB): k0 writes them,
    // k1 reads them, k2 fully overwrites d_out afterwards (same stream).
    unsigned short* whi = (unsigned short*)d_out;       // 32 KB
    unsigned short* wlo = whi + 256*64;                 // 32 KB

    hipLaunchKernelGGL(k_precompute,   dim3(1),    dim3(256), 0, stream,
                       ff, w_in, Kc, whi, wlo);
    hipLaunchKernelGGL(k1_proj_circ,   dim3(4096), dim3(256), 0, stream,
                       x, whi, wlo, b_in, Kc, s);
    hipLaunchKernelGGL(k2_dw_gelu_out, dim3(4096), dim3(256), 0, stream,
                       s, w_dw, b_dw, w_out, b_out, out);
}

// Round 6
// 548.503 us; speedup vs baseline: 1.9170x; 1.0112x over previous
//
#include <hip/hip_runtime.h>
#include <hip/hip_bf16.h>

// DFFN fused implementation. R6: fix R5's self-race — wob (k2's MFMA A-operand
// table) moved from d_out-carved scratch into d_ws. R5 had k2 reading wob from
// d_out while k2 blocks concurrently overwrote d_out -> NaN. whi/wlo remain in
// d_out (read only by k1, which retires before k2 launches: stream-ordered).
// Pipeline: proj_in(1x1, MFMA hi/lo bf16 = fp32-accurate) -> per-channel 8x8
// circular conv (== rfft2*filter*irfft2 on flat-reshaped "patches" = 1x64
// column runs) -> dw3x3 -> GELU gate -> proj_out(1x1, MFMA bf16).
// Intermediate s: channels-last bf16 [b][h][w][c2].

#define BATCH 4
#define CIN   64
#define C2    256
#define HH    256
#define WW    256
#define HW    (HH*WW)

using bf16 = __hip_bfloat16;
typedef short bf16x8 __attribute__((ext_vector_type(8)));
typedef float f32x4  __attribute__((ext_vector_type(4)));

__device__ __forceinline__ unsigned f2bf_bits(float v){
    unsigned u = __float_as_uint(v);
    return (u + 0x7fffu + ((u >> 16) & 1u)) >> 16;          // RNE
}
__device__ __forceinline__ float bfbits2f(unsigned hu){ return __uint_as_float(hu << 16); }

__device__ __forceinline__ void unpack8(uint4 v, float* f) {
    unsigned a0 = v.x, a1 = v.y, a2 = v.z, a3 = v.w;
    f[0] = __uint_as_float(a0 << 16); f[1] = __uint_as_float(a0 & 0xffff0000u);
    f[2] = __uint_as_float(a1 << 16); f[3] = __uint_as_float(a1 & 0xffff0000u);
    f[4] = __uint_as_float(a2 << 16); f[5] = __uint_as_float(a2 & 0xffff0000u);
    f[6] = __uint_as_float(a3 << 16); f[7] = __uint_as_float(a3 & 0xffff0000u);
}

// ---------------------------------------------------------------------------
// K0: (a) per-channel 8x8 circular-conv kernel from the rfft2 filter;
//     (b) hi/lo bf16 split of w_in into B-operand tables whi/wlo [c2][cin];
//     (c) bf16 w_out table wob [c_out][128] for k2's MFMA A-frags.
// ---------------------------------------------------------------------------
__global__ void k_precompute(const float* __restrict__ F,
                             const float* __restrict__ w_in,
                             const float* __restrict__ w_out,
                             float* __restrict__ Kc,
                             unsigned short* __restrict__ whi,
                             unsigned short* __restrict__ wlo,
                             unsigned short* __restrict__ wob)
{
    const int c = threadIdx.x;                   // 256 threads = 256 channels
    const float R = 0.7071067811865476f;
    const float C8[8] = {1.f, R, 0.f, -R, -1.f, -R, 0.f, R};
    const float S8[8] = {0.f, R, 1.f, R, 0.f, -R, -1.f, -R};

    // (b) w_in split
    for (int k = 0; k < 64; ++k) {
        float v = w_in[c*64 + k];
        unsigned hu = f2bf_bits(v);
        whi[c*64 + k] = (unsigned short)hu;
        wlo[c*64 + k] = (unsigned short)f2bf_bits(v - bfbits2f(hu));
    }
    // (c) w_out bf16 table
    for (int e = c; e < 64*128; e += 256)
        wob[e] = (unsigned short)f2bf_bits(w_out[e]);

    // (a) conv kernel
    float Fv[8][5];
    for (int u = 0; u < 8; ++u)
        for (int v = 0; v < 5; ++v)
            Fv[u][v] = F[c*40 + u*5 + v];

    float ReG[5][8], ImG[5][8];
    for (int v = 0; v < 5; ++v)
        for (int m = 0; m < 8; ++m) {
            float re = 0.f, im = 0.f;
            for (int u = 0; u < 8; ++u) {
                int idx = (u*m) & 7;
                re += Fv[u][v] * C8[idx];
                im += Fv[u][v] * S8[idx];
            }
            ReG[v][m] = re * 0.125f;
            ImG[v][m] = im * 0.125f;
        }

    for (int m = 0; m < 8; ++m)
        for (int n = 0; n < 8; ++n) {
            float acc = 0.f;
            for (int v = 0; v < 5; ++v) {
                float wv = (v == 0 || v == 4) ? 0.125f : 0.25f;
                int idx = (v*n) & 7;
                acc += wv * (ReG[v][m]*C8[idx] - ImG[v][m]*S8[idx]);
            }
            Kc[c*64 + m*8 + n] = acc;
        }
}

// ---------------------------------------------------------------------------
// K1 (unchanged from R4): per (b, h, 64-col run): proj_in via MFMA
// (m=px16, n=c2, k=cin) with hi/lo bf16 split, then VALU circular conv,
// bf16 channels-last store.
// ---------------------------------------------------------------------------
__global__ __launch_bounds__(256) void k1_proj_circ(
    const float* __restrict__ x,
    const unsigned short* __restrict__ whi,
    const unsigned short* __restrict__ wlo,
    const float* __restrict__ b_in, const float* __restrict__ Kc,
    bf16* __restrict__ s)
{
    __shared__ __align__(16) unsigned short xs_hi[64*72];   // 9 KB
    __shared__ __align__(16) unsigned short xs_lo[64*72];   // 9 KB
    __shared__ __align__(16) unsigned short ysT[64*258];    // 32.25 KB

    const int tid = threadIdx.x;
    const int bid = blockIdx.x;
    const int run = bid & 3;
    const int h   = (bid >> 2) & 255;
    const int b   = bid >> 10;

    const float* xb = x + (long)b * CIN * HW + h * WW + run * 64;

    // stage x tile (64 cin x 64 px), hi/lo bf16 split, transposed [px][cin]
#pragma unroll
    for (int i = 0; i < 16; ++i) {
        int e = i*256 + tid;
        int c = e >> 6, col = e & 63;
        float v = xb[(long)c * HW + col];
        unsigned hu = f2bf_bits(v);
        unsigned lu = f2bf_bits(v - bfbits2f(hu));
        xs_hi[col*72 + c] = (unsigned short)hu;
        xs_lo[col*72 + c] = (unsigned short)lu;
    }
    __syncthreads();

    const int wv = tid >> 6, lane = tid & 63;
    const int quad = lane >> 4, n16 = lane & 15;

    // wave wv handles c2 in [wv*64, wv*64+64)
    for (int nt = 0; nt < 4; ++nt) {                 // rolled: low pressure
        const int c2 = wv*64 + nt*16 + n16;
        f32x4 acc[4];
#pragma unroll
        for (int mt = 0; mt < 4; ++mt) acc[mt] = (f32x4){0.f,0.f,0.f,0.f};

#pragma unroll
        for (int k = 0; k < 2; ++k) {
            const bf16x8 bh = *(const bf16x8*)&whi[c2*64 + k*32 + quad*8];
            const bf16x8 bl = *(const bf16x8*)&wlo[c2*64 + k*32 + quad*8];
#pragma unroll
            for (int mt = 0; mt < 4; ++mt) {
                const int o = (mt*16 + n16)*72 + k*32 + quad*8;
                const bf16x8 a_h = *(const bf16x8*)&xs_hi[o];
                const bf16x8 a_l = *(const bf16x8*)&xs_lo[o];
                acc[mt] = __builtin_amdgcn_mfma_f32_16x16x32_bf16(a_h, bh, acc[mt], 0, 0, 0);
                acc[mt] = __builtin_amdgcn_mfma_f32_16x16x32_bf16(a_l, bh, acc[mt], 0, 0, 0);
                acc[mt] = __builtin_amdgcn_mfma_f32_16x16x32_bf16(a_h, bl, acc[mt], 0, 0, 0);
            }
        }
        const float bv = b_in[c2];
#pragma unroll
        for (int mt = 0; mt < 4; ++mt)
#pragma unroll
            for (int r = 0; r < 4; ++r) {
                int u = mt*16 + quad*4 + r;          // D row = quad*4 + reg
                ysT[u*258 + c2] = (unsigned short)f2bf_bits(acc[mt][r] + bv);
            }
    }
    __syncthreads();

    // circular conv: thread = channel tid
    const float* Kp = Kc + tid*64;
    float o[64];
#pragma unroll
    for (int i = 0; i < 64; ++i) o[i] = 0.f;

#pragma unroll
    for (int a = 0; a < 8; ++a) {
        for (int m = 0; m < 8; ++m) {
            int r = (a - m) & 7;
            float yy[8];
#pragma unroll
            for (int q = 0; q < 8; ++q)
                yy[q] = bfbits2f((unsigned)ysT[(r*8 + q)*258 + tid]);
#pragma unroll
            for (int n = 0; n < 8; ++n) {
                float kk = Kp[m*8 + n];
#pragma unroll
                for (int bb = 0; bb < 8; ++bb)
                    o[a*8 + bb] += kk * yy[(bb - n) & 7];
            }
        }
    }

#pragma unroll
    for (int u = 0; u < 64; ++u)
        ysT[u*258 + tid] = (unsigned short)f2bf_bits(o[u]);
    __syncthreads();

    bf16* sp = s + (((long)(b * HH + h) * WW) + run * 64) * C2;
    const int uo = tid >> 5;          // 0..7
    const int c0 = (tid & 31) * 8;    // 0..248
#pragma unroll
    for (int pass = 0; pass < 8; ++pass) {
        int u = pass * 8 + uo;
        const unsigned* yp = (const unsigned*)&ysT[u*258 + c0];
        uint4 val = make_uint4(yp[0], yp[1], yp[2], yp[3]);
        *(uint4*)(sp + (long)u * C2 + c0) = val;
    }
}

// ---------------------------------------------------------------------------
// K2: per (b, h, run of 64 px): dw3x3 + bias -> GELU gate -> MFMA proj_out.
// Phase 1: thread = (px=lane, chunk-pair of 8 ch), 4 tasks; 18 x 16B global
//   loads per task; g packed bf16 into LDS gs[px][c] stride 136 (16B aligned).
// Phase 2: MFMA 16x16x32_bf16, m=c_out(64), n=px(64), k=c(128). Wave rg owns
//   px-tile rg*16; A-frags from ws-resident wob table, B-frags ds_read_b128.
// LDS 17 KB -> 8 blocks/CU ceiling.
// ---------------------------------------------------------------------------
__global__ __launch_bounds__(256) void k2_dw_gelu_out(
    const bf16* __restrict__ s, const float* __restrict__ w_dw,
    const float* __restrict__ b_dw,
    const unsigned short* __restrict__ wob,
    const float* __restrict__ b_out, float* __restrict__ out)
{
    __shared__ __align__(16) unsigned short gs[64*136];   // 17 KB, [px][c]

    const int tid = threadIdx.x;
    const int l   = ((blockIdx.x & 7) << 9) | (blockIdx.x >> 3);  // XCD swizzle
    const int run = l & 3;
    const int h   = (l >> 2) & 255;
    const int b   = l >> 10;
    const int wl  = tid & 63, rg = tid >> 6;
    const int w   = run*64 + wl;

#pragma unroll
    for (int i = 0; i < 4; ++i) {
        const int c0 = __builtin_amdgcn_readfirstlane((rg + 4*i) * 8); // 0..120, uniform
        float t1[8], t2[8];
#pragma unroll
        for (int j = 0; j < 8; ++j) { t1[j] = b_dw[c0+j]; t2[j] = b_dw[c0+128+j]; }

#pragma unroll
        for (int dy = 0; dy < 3; ++dy) {
            const int hy = h + dy - 1;
            if ((unsigned)hy >= HH) continue;          // wave-uniform
#pragma unroll
            for (int dx = 0; dx < 3; ++dx) {
                const int wx = w + dx - 1;
                if ((unsigned)wx < WW) {               // diverges only at image edge
                    const bf16* p = s + (((long)(b*HH + hy)*WW + wx) * C2 + c0);
                    uint4 v1 = *(const uint4*)p;
                    uint4 v2 = *(const uint4*)(p + 128);
                    float f1[8], f2[8];
                    unpack8(v1, f1); unpack8(v2, f2);
#pragma unroll
                    for (int j = 0; j < 8; ++j) {
                        t1[j] += f1[j] * w_dw[(c0+j)*9       + dy*3 + dx];
                        t2[j] += f2[j] * w_dw[(c0+128+j)*9   + dy*3 + dx];
                    }
                }
            }
        }
        // GELU(t1)*t2, exact erf; pack to bf16 pairs, store [px=wl][c0..c0+7]
        unsigned r4[4];
#pragma unroll
        for (int j = 0; j < 4; ++j) {
            float ga = t1[2*j]   * 0.5f * (1.0f + erff(t1[2*j]   * 0.7071067811865476f)) * t2[2*j];
            float gb = t1[2*j+1] * 0.5f * (1.0f + erff(t1[2*j+1] * 0.7071067811865476f)) * t2[2*j+1];
            r4[j] = f2bf_bits(ga) | (f2bf_bits(gb) << 16);
        }
        *(uint4*)&gs[wl*136 + c0] = make_uint4(r4[0], r4[1], r4[2], r4[3]);
    }
    __syncthreads();

    // Phase 2: MFMA proj_out. Wave rg -> px-tile rg*16..+15.
    const int quad = wl >> 4, n16 = wl & 15;
    const int px   = rg*16 + n16;

    f32x4 acc[4];                                  // mt = c_out tile
#pragma unroll
    for (int mt = 0; mt < 4; ++mt) acc[mt] = (f32x4){0.f,0.f,0.f,0.f};

#pragma unroll
    for (int ks = 0; ks < 4; ++ks) {
        const bf16x8 bfrag = *(const bf16x8*)&gs[px*136 + ks*32 + quad*8];
#pragma unroll
        for (int mt = 0; mt < 4; ++mt) {
            const bf16x8 afrag = *(const bf16x8*)&wob[(mt*16 + n16)*128 + ks*32 + quad*8];
            acc[mt] = __builtin_amdgcn_mfma_f32_16x16x32_bf16(afrag, bfrag, acc[mt], 0, 0, 0);
        }
    }

    // D: col=lane&15 = n = px-within-tile, row = quad*4+r = c_out-within-tile
    float* op = out + (long)b * CIN * HW + h * WW + run*64 + rg*16 + n16;
#pragma unroll
    for (int mt = 0; mt < 4; ++mt)
#pragma unroll
        for (int r = 0; r < 4; ++r) {
            const int c_out = mt*16 + quad*4 + r;
            op[(long)c_out * HW] = acc[mt][r] + b_out[c_out];
        }
}

// ---------------------------------------------------------------------------
extern "C" void kernel_launch(void* const* d_in, const int* in_sizes, int n_in,
                              void* d_out, int out_size, void* d_ws, size_t ws_size,
                              hipStream_t stream) {
    const float* x     = (const float*)d_in[0];
    const float* w_in  = (const float*)d_in[1];
    const float* b_in  = (const float*)d_in[2];
    const float* ff    = (const float*)d_in[3];
    const float* w_dw  = (const float*)d_in[4];
    const float* b_dw  = (const float*)d_in[5];
    const float* w_out = (const float*)d_in[6];
    const float* b_out = (const float*)d_in[7];
    float* out = (float*)d_out;

    // d_ws layout: Kc [0,64K) | wob [64K,80K) | s [80K, +128MB)
    float*          Kc  = (float*)d_ws;
    unsigned short* wob = (unsigned short*)((char*)d_ws + 65536);   // 16 KB
    bf16*           s   = (bf16*)((char*)d_ws + 65536 + 16384);

    // whi/wlo in d_out is safe: only k1 reads them, and k1 fully retires
    // (stream order) before k2 begins overwriting d_out.
    unsigned short* whi = (unsigned short*)d_out;       // 32 KB
    unsigned short* wlo = whi + 256*64;                 // 32 KB

    hipLaunchKernelGGL(k_precompute,   dim3(1),    dim3(256), 0, stream,
                       ff, w_in, w_out, Kc, whi, wlo, wob);
    hipLaunchKernelGGL(k1_proj_circ,   dim3(4096), dim3(256), 0, stream,
                       x, whi, wlo, b_in, Kc, s);
    hipLaunchKernelGGL(k2_dw_gelu_out, dim3(4096), dim3(256), 0, stream,
                       s, w_dw, b_dw, wob, b_out, out);
}